// Round 7
// baseline (325.522 us; speedup 1.0000x reference)
//
#include <hip/hip_runtime.h>
#include <cstdint>
#include <cstring>

// ---------------------------------------------------------------------------
// GQA forward, all-bf16 MFMA pipeline.  B=2, L=2048, D=2048, HQ=32, HKV=8, HD=64.
// Round 11 (= Round 10 with compile fix): GEMMs rebuilt on the 8-wave / BK=64
// double-buffered structure.
//   - gemm_qkv: 256x256 tile, 512 thr (8 waves, 2x4), dbuf LDS 128 KB,
//     burst-prefetch next K-tile before compute, ONE __syncthreads per K-tile
//     (drain hidden under ~64 MFMA + 28 ds_read of compute).  Both-sides
//     chunk-XOR swizzle (same algebra as the verified attn staging).
//     Epilogue via per-wave LDS transpose -> dwordx4 bf16 stores.
//   - gemm_out: 128x256 tile (256 blocks = full CU coverage), same core,
//     direct coalesced f32 dword stores.
//   - attn: exactly the verified Round-7 kernel (97-108 us).
// ---------------------------------------------------------------------------

#define L_SEQ 2048
#define D_MODEL 2048
#define M_ROWS 4096              // B*L
#define KV_COLS 512              // HKV*HD
#define ATTN_SCALE 0.18033688011112042f   // log2(e)/sqrt(64), folded into K

typedef __bf16 bf16x8 __attribute__((ext_vector_type(8)));
typedef float f32x4 __attribute__((ext_vector_type(4)));
typedef float f32x16 __attribute__((ext_vector_type(16)));

__device__ __forceinline__ f32x4 zero4() {
    f32x4 v; v[0] = 0.f; v[1] = 0.f; v[2] = 0.f; v[3] = 0.f; return v;
}

__device__ __forceinline__ unsigned short f2bf(float x) {
    unsigned u = __builtin_bit_cast(unsigned, x);
    u = (u + 0x7FFFu + ((u >> 16) & 1u)) >> 16;   // RNE
    return (unsigned short)u;
}

__device__ __forceinline__ unsigned pk_bf16(float a, float b) {
#if __has_builtin(__builtin_amdgcn_cvt_pk_bf16_f32)
    typedef __bf16 bf16x2 __attribute__((ext_vector_type(2)));
    bf16x2 r = __builtin_amdgcn_cvt_pk_bf16_f32(a, b);
    return __builtin_bit_cast(unsigned, r);
#else
    return (unsigned)f2bf(a) | ((unsigned)f2bf(b) << 16);
#endif
}

__device__ __forceinline__ f32x4 mfma16(uint4 a, uint4 b, f32x4 c) {
    return __builtin_amdgcn_mfma_f32_16x16x32_bf16(
        __builtin_bit_cast(bf16x8, a), __builtin_bit_cast(bf16x8, b), c, 0, 0, 0);
}
__device__ __forceinline__ f32x16 mfma32(uint4 a, uint4 b, f32x16 c) {
    return __builtin_amdgcn_mfma_f32_32x32x16_bf16(
        __builtin_bit_cast(bf16x8, a), __builtin_bit_cast(bf16x8, b), c, 0, 0, 0);
}

__device__ __forceinline__ void gl_lds16(const unsigned short* g, unsigned short* l) {
    __builtin_amdgcn_global_load_lds(
        (const __attribute__((address_space(1))) unsigned int*)g,
        (__attribute__((address_space(3))) unsigned int*)l, 16, 0, 0);
}

#if __has_builtin(__builtin_amdgcn_exp2f)
#define EXP2F(x) __builtin_amdgcn_exp2f(x)
#else
#define EXP2F(x) exp2f(x)
#endif

// a.hi <-> b.lo lane exchange
__device__ __forceinline__ void permswap32(unsigned& a, unsigned& b) {
    asm("v_permlane32_swap_b32 %0, %1" : "+v"(a), "+v"(b));
}

// ---------------------------------------------------------------------------
// prep kernels
// ---------------------------------------------------------------------------

__global__ __launch_bounds__(256) void cast_x_kernel(const float* __restrict__ in,
                                                     unsigned short* __restrict__ out,
                                                     int n4) {
    int i = blockIdx.x * 256 + threadIdx.x;
    if (i >= n4) return;
    float4 v = ((const float4*)in)[i];
    uint2 o;
    o.x = pk_bf16(v.x, v.y);
    o.y = pk_bf16(v.z, v.w);
    ((uint2*)out)[i] = o;
}

__global__ __launch_bounds__(256) void transpose_cast_kernel(const float* __restrict__ in,
                                                             unsigned short* __restrict__ out,
                                                             int N, int row_off) {
    __shared__ float tile[32][33];
    const int n0 = blockIdx.x * 32, k0 = blockIdx.y * 32;
    const int tc = threadIdx.x & 31, tr = threadIdx.x >> 5;
#pragma unroll
    for (int i = 0; i < 4; ++i)
        tile[tr + i * 8][tc] = in[(size_t)(k0 + tr + i * 8) * N + n0 + tc];
    __syncthreads();
#pragma unroll
    for (int i = 0; i < 4; ++i)
        out[(size_t)(row_off + n0 + tr + i * 8) * 2048 + k0 + tc] = f2bf(tile[tc][tr + i * 8]);
}

// Vb [B*L, 512] bf16  ->  Vt [(b*8+kvh)*64+d, 2048] bf16  (per-b transpose)
__global__ __launch_bounds__(256) void transpose_v_kernel(const unsigned short* __restrict__ Vb,
                                                          unsigned short* __restrict__ Vt) {
    __shared__ unsigned short tile[32][33];
    const int c0 = blockIdx.x * 32, l0 = blockIdx.y * 32, b = blockIdx.z;
    const int tc = threadIdx.x & 31, tr = threadIdx.x >> 5;
#pragma unroll
    for (int i = 0; i < 4; ++i)
        tile[tr + i * 8][tc] = Vb[(size_t)(b * 2048 + l0 + tr + i * 8) * KV_COLS + c0 + tc];
    __syncthreads();
#pragma unroll
    for (int i = 0; i < 4; ++i)
        Vt[(size_t)(b * 512 + c0 + tr + i * 8) * 2048 + l0 + tc] = tile[tc][tr + i * 8];
}

// ---------------------------------------------------------------------------
// GEMM1 (8-wave, 256x256, BK=64, dbuf): X[4096,2048] * Wt[3072,2048]^T
//   -> Q [4096,2048], K [4096,512] (pre-scaled), V [4096,512], all bf16
// ---------------------------------------------------------------------------

__global__ __launch_bounds__(512, 1) void gemm_qkv_kernel(
    const unsigned short* __restrict__ Xb, const unsigned short* __restrict__ Wt,
    const float* __restrict__ bq, const float* __restrict__ bk, const float* __restrict__ bv,
    unsigned short* __restrict__ Qb, unsigned short* __restrict__ Kb,
    unsigned short* __restrict__ Vb) {
    __shared__ __align__(16) char smem[131072];   // 2 x (A 32KB + B 32KB)

    const int mb = blockIdx.x, nb = blockIdx.y;
    const int tid = threadIdx.x;
    const int w = tid >> 6, lane = tid & 63;
    const int wm = w >> 2, wn = w & 3;            // 2 x 4 wave grid
    const int lr = lane & 15, lg = lane >> 4;
    const int rr = lane >> 3, cp = lane & 7;      // staging: 8 rows x 8 chunks

    f32x4 acc[8][4];
#pragma unroll
    for (int i = 0; i < 8; ++i)
#pragma unroll
        for (int j = 0; j < 4; ++j) acc[i][j] = zero4();

    const size_t arow0 = (size_t)mb * 256;
    const size_t brow0 = (size_t)nb * 256;

    // stage K-tile kt into buffer d: A [256][64] + B [256][64], chunk-XOR src
    auto stage = [&](int kt, int d) {
        const int k8 = kt * 64 + ((cp ^ rr) * 8);
#pragma unroll
        for (int s = 0; s < 4; ++s) {
            const int c = w * 4 + s;                       // 32 chunks of 1 KB
            gl_lds16(Xb + (arow0 + c * 8 + rr) * 2048 + k8,
                     (unsigned short*)(smem + d * 65536 + c * 1024));
            gl_lds16(Wt + (brow0 + c * 8 + rr) * 2048 + k8,
                     (unsigned short*)(smem + d * 65536 + 32768 + c * 1024));
        }
    };

    stage(0, 0);
    __syncthreads();

    for (int t = 0; t < 32; ++t) {
        const int d = t & 1;
        if (t < 31) stage(t + 1, d ^ 1);   // in flight across whole compute

        const char* Ab = smem + d * 65536;
        const char* Bb = smem + d * 65536 + 32768;
        auto rdA = [&](int mi, int k) -> uint4 {
            const int row = wm * 128 + mi * 16 + lr;
            return *(const uint4*)(Ab + row * 128 + (((k * 4 + lg) ^ (lr & 7)) * 16));
        };
        auto rdB = [&](int nj, int k) -> uint4 {
            const int row = wn * 64 + nj * 16 + lr;
            return *(const uint4*)(Bb + row * 128 + (((k * 4 + lg) ^ (lr & 7)) * 16));
        };

        uint4 fa[4][2], fb[2][2];
        // ---- phase 0: mi 0..3 x nj 0..1 ----
#pragma unroll
        for (int mi = 0; mi < 4; ++mi) { fa[mi][0] = rdA(mi, 0); fa[mi][1] = rdA(mi, 1); }
#pragma unroll
        for (int nj = 0; nj < 2; ++nj) { fb[nj][0] = rdB(nj, 0); fb[nj][1] = rdB(nj, 1); }
        __builtin_amdgcn_s_setprio(1);
#pragma unroll
        for (int mi = 0; mi < 4; ++mi)
#pragma unroll
            for (int nj = 0; nj < 2; ++nj) {
                acc[mi][nj] = mfma16(fa[mi][0], fb[nj][0], acc[mi][nj]);
                acc[mi][nj] = mfma16(fa[mi][1], fb[nj][1], acc[mi][nj]);
            }
        __builtin_amdgcn_s_setprio(0);
        // ---- phase 1: mi 0..3 x nj 2..3 ----
#pragma unroll
        for (int nj = 0; nj < 2; ++nj) { fb[nj][0] = rdB(nj + 2, 0); fb[nj][1] = rdB(nj + 2, 1); }
        __builtin_amdgcn_s_setprio(1);
#pragma unroll
        for (int mi = 0; mi < 4; ++mi)
#pragma unroll
            for (int nj = 0; nj < 2; ++nj) {
                acc[mi][nj + 2] = mfma16(fa[mi][0], fb[nj][0], acc[mi][nj + 2]);
                acc[mi][nj + 2] = mfma16(fa[mi][1], fb[nj][1], acc[mi][nj + 2]);
            }
        __builtin_amdgcn_s_setprio(0);
        // ---- phase 2: mi 4..7 x nj 2..3 ----
#pragma unroll
        for (int mi = 0; mi < 4; ++mi) { fa[mi][0] = rdA(mi + 4, 0); fa[mi][1] = rdA(mi + 4, 1); }
        __builtin_amdgcn_s_setprio(1);
#pragma unroll
        for (int mi = 0; mi < 4; ++mi)
#pragma unroll
            for (int nj = 0; nj < 2; ++nj) {
                acc[mi + 4][nj + 2] = mfma16(fa[mi][0], fb[nj][0], acc[mi + 4][nj + 2]);
                acc[mi + 4][nj + 2] = mfma16(fa[mi][1], fb[nj][1], acc[mi + 4][nj + 2]);
            }
        __builtin_amdgcn_s_setprio(0);
        // ---- phase 3: mi 4..7 x nj 0..1 (re-read B0..1) ----
#pragma unroll
        for (int nj = 0; nj < 2; ++nj) { fb[nj][0] = rdB(nj, 0); fb[nj][1] = rdB(nj, 1); }
        __builtin_amdgcn_s_setprio(1);
#pragma unroll
        for (int mi = 0; mi < 4; ++mi)
#pragma unroll
            for (int nj = 0; nj < 2; ++nj) {
                acc[mi + 4][nj] = mfma16(fa[mi][0], fb[nj][0], acc[mi + 4][nj]);
                acc[mi + 4][nj] = mfma16(fa[mi][1], fb[nj][1], acc[mi + 4][nj]);
            }
        __builtin_amdgcn_s_setprio(0);

        __syncthreads();   // next tile landed; all reads of cur buffer done
    }

    // ---- epilogue: per-wave LDS transpose -> dwordx4 bf16 stores ----
    const int nbase = nb * 256;
    unsigned short* outp; int ldo, noff; const float* bias; float scale;
    if (nbase < 2048)      { outp = Qb; ldo = 2048; noff = 0;    bias = bq; scale = 1.f; }
    else if (nbase < 2560) { outp = Kb; ldo = 512;  noff = 2048; bias = bk; scale = ATTN_SCALE; }
    else                   { outp = Vb; ldo = 512;  noff = 2560; bias = bv; scale = 1.f; }

    float* ep = (float*)(smem + w * 16384);   // [128 rows][32 cols] f32 per wave
#pragma unroll
    for (int pair = 0; pair < 2; ++pair) {
#pragma unroll
        for (int mi = 0; mi < 8; ++mi)
#pragma unroll
            for (int jj = 0; jj < 2; ++jj)
#pragma unroll
                for (int r = 0; r < 4; ++r)
                    ep[(mi * 16 + lg * 4 + r) * 32 + jj * 16 + lr] = acc[mi][pair * 2 + jj][r];
        __builtin_amdgcn_s_waitcnt(0);   // wave-local LDS write->read ordering
#pragma unroll
        for (int p = 0; p < 8; ++p) {
            const int row = p * 16 + (lane >> 2);
            const int q = lane & 3;
            const float* v = ep + row * 32 + q * 8;
            const int ncol = nbase + wn * 64 + pair * 32 + q * 8 - noff;
            const float4 b0 = *(const float4*)(bias + ncol);
            const float4 b1 = *(const float4*)(bias + ncol + 4);
            uint4 o;
            o.x = pk_bf16((v[0] + b0.x) * scale, (v[1] + b0.y) * scale);
            o.y = pk_bf16((v[2] + b0.z) * scale, (v[3] + b0.w) * scale);
            o.z = pk_bf16((v[4] + b1.x) * scale, (v[5] + b1.y) * scale);
            o.w = pk_bf16((v[6] + b1.z) * scale, (v[7] + b1.w) * scale);
            *(uint4*)(outp + (size_t)(mb * 256 + wm * 128 + row) * ldo + ncol) = o;
        }
        __builtin_amdgcn_s_waitcnt(0);   // reads drained before next-pair overwrite
    }
}

// ---------------------------------------------------------------------------
// GEMM2 (8-wave, 128x256, BK=64, dbuf): ctx[4096,2048] * Wot[2048,2048]^T
//   + bo -> fp32 out [4096,2048].  256 blocks = full CU coverage.
// ---------------------------------------------------------------------------

__global__ __launch_bounds__(512, 1) void gemm_out_kernel(
    const unsigned short* __restrict__ Cb, const unsigned short* __restrict__ Wot,
    const float* __restrict__ bo, float* __restrict__ out) {
    __shared__ __align__(16) char smem[98304];   // 2 x (A 16KB + B 32KB)

    const int mb = blockIdx.x, nb = blockIdx.y;
    const int tid = threadIdx.x;
    const int w = tid >> 6, lane = tid & 63;
    const int wm = w >> 2, wn = w & 3;
    const int lr = lane & 15, lg = lane >> 4;
    const int rr = lane >> 3, cp = lane & 7;

    f32x4 acc[4][4];
#pragma unroll
    for (int i = 0; i < 4; ++i)
#pragma unroll
        for (int j = 0; j < 4; ++j) acc[i][j] = zero4();

    const size_t arow0 = (size_t)mb * 128;
    const size_t brow0 = (size_t)nb * 256;

    auto stage = [&](int kt, int d) {
        const int k8 = kt * 64 + ((cp ^ rr) * 8);
#pragma unroll
        for (int s = 0; s < 2; ++s) {                      // A: 16 chunks
            const int c = w * 2 + s;
            gl_lds16(Cb + (arow0 + c * 8 + rr) * 2048 + k8,
                     (unsigned short*)(smem + d * 49152 + c * 1024));
        }
#pragma unroll
        for (int s = 0; s < 4; ++s) {                      // B: 32 chunks
            const int c = w * 4 + s;
            gl_lds16(Wot + (brow0 + c * 8 + rr) * 2048 + k8,
                     (unsigned short*)(smem + d * 49152 + 16384 + c * 1024));
        }
    };

    stage(0, 0);
    __syncthreads();

    for (int t = 0; t < 32; ++t) {
        const int d = t & 1;
        if (t < 31) stage(t + 1, d ^ 1);

        const char* Ab = smem + d * 49152;
        const char* Bb = smem + d * 49152 + 16384;
        auto rdA = [&](int mi, int k) -> uint4 {
            const int row = wm * 64 + mi * 16 + lr;
            return *(const uint4*)(Ab + row * 128 + (((k * 4 + lg) ^ (lr & 7)) * 16));
        };
        auto rdB = [&](int nj, int k) -> uint4 {
            const int row = wn * 64 + nj * 16 + lr;
            return *(const uint4*)(Bb + row * 128 + (((k * 4 + lg) ^ (lr & 7)) * 16));
        };

        uint4 fa[4][2], fb[2][2];
        // ---- phase 0: mi 0..3 x nj 0..1 ----
#pragma unroll
        for (int mi = 0; mi < 4; ++mi) { fa[mi][0] = rdA(mi, 0); fa[mi][1] = rdA(mi, 1); }
#pragma unroll
        for (int nj = 0; nj < 2; ++nj) { fb[nj][0] = rdB(nj, 0); fb[nj][1] = rdB(nj, 1); }
        __builtin_amdgcn_s_setprio(1);
#pragma unroll
        for (int mi = 0; mi < 4; ++mi)
#pragma unroll
            for (int nj = 0; nj < 2; ++nj) {
                acc[mi][nj] = mfma16(fa[mi][0], fb[nj][0], acc[mi][nj]);
                acc[mi][nj] = mfma16(fa[mi][1], fb[nj][1], acc[mi][nj]);
            }
        __builtin_amdgcn_s_setprio(0);
        // ---- phase 1: mi 0..3 x nj 2..3 ----
#pragma unroll
        for (int nj = 0; nj < 2; ++nj) { fb[nj][0] = rdB(nj + 2, 0); fb[nj][1] = rdB(nj + 2, 1); }
        __builtin_amdgcn_s_setprio(1);
#pragma unroll
        for (int mi = 0; mi < 4; ++mi)
#pragma unroll
            for (int nj = 0; nj < 2; ++nj) {
                acc[mi][nj + 2] = mfma16(fa[mi][0], fb[nj][0], acc[mi][nj + 2]);
                acc[mi][nj + 2] = mfma16(fa[mi][1], fb[nj][1], acc[mi][nj + 2]);
            }
        __builtin_amdgcn_s_setprio(0);

        __syncthreads();
    }

    // ---- epilogue: direct coalesced f32 dword stores ----
#pragma unroll
    for (int mi = 0; mi < 4; ++mi) {
        const int mrow = mb * 128 + wm * 64 + mi * 16 + lg * 4;
#pragma unroll
        for (int nj = 0; nj < 4; ++nj) {
            const int ncol = nb * 256 + wn * 64 + nj * 16 + lr;
            const float bb = bo[ncol];
#pragma unroll
            for (int r = 0; r < 4; ++r)
                out[(size_t)(mrow + r) * 2048 + ncol] = acc[mi][nj][r] + bb;
        }
    }
}

// ---------------------------------------------------------------------------
// Attention (Round-7 verified): block = 512 thr = 8 waves; each wave owns
// 64 q (2 q-frags, u=0/1) of one q-head; block covers 512 q.  Grid
// 4 x 32 x 2 = 256 blocks.  K tile [128 k][64 d] and V^T tile [64 d][128 k]
// double-buffered (64 KB LDS); next tile staged before compute; one
// __syncthreads per iter.  permswap P assembly; setprio around MFMA.
// ---------------------------------------------------------------------------

__global__ __launch_bounds__(512, 2) void attn_kernel(const unsigned short* __restrict__ Qb,
                                                      const unsigned short* __restrict__ Kb,
                                                      const unsigned short* __restrict__ Vtg,
                                                      unsigned short* __restrict__ ctx) {
    __shared__ __align__(16) unsigned short smem[32768];   // 64 KB

    const int qt = blockIdx.x, hq = blockIdx.y, b = blockIdx.z;
    const int kvh = hq >> 2;
    const int tid = threadIdx.x;
    const int w = tid >> 6, lane = tid & 63;
    const int l31 = lane & 31, h = lane >> 5;

    const int qbase = qt * 512 + w * 64;
    uint4 qf[2][4];
#pragma unroll
    for (int u = 0; u < 2; ++u) {
        const unsigned short* qp =
            Qb + (size_t)(b * L_SEQ + qbase + u * 32 + l31) * 2048 + hq * 64;
#pragma unroll
        for (int dh = 0; dh < 4; ++dh)
            qf[u][dh] = *(const uint4*)(qp + dh * 16 + h * 8);
    }

    f32x16 o00, o01, o10, o11;
#pragma unroll
    for (int r = 0; r < 16; ++r) { o00[r] = 0.f; o01[r] = 0.f; o10[r] = 0.f; o11[r] = 0.f; }
    float l_acc0 = 0.f, l_acc1 = 0.f;

    const size_t kbase = (size_t)(b * L_SEQ) * KV_COLS + kvh * 64;
    const size_t vbase = (size_t)((b * 8 + kvh) * 64) * 2048;

    const int rrk = lane >> 3, cpk = lane & 7;
    const int drv = lane >> 4, cpv = lane & 15;

    unsigned short* ksC = smem;
    unsigned short* vtC = smem + 8192;
    unsigned short* ksN = smem + 16384;
    unsigned short* vtN = smem + 24576;

    auto stage = [&](int T, unsigned short* KS, unsigned short* VT) {
        const int k0s = T * 128;
#pragma unroll
        for (int s = 0; s < 2; ++s) {
            const int blk = w * 2 + s;
            gl_lds16(Kb + kbase + (size_t)(k0s + blk * 8 + rrk) * KV_COLS + ((cpk ^ rrk) * 8),
                     KS + blk * 512);
            const int d = blk * 4 + drv;
            gl_lds16(Vtg + vbase + (size_t)d * 2048 + k0s + ((cpv ^ (d & 15)) * 8),
                     VT + blk * 512);
        }
    };

    stage(0, ksC, vtC);
    __syncthreads();

    for (int t = 0; t < 16; ++t) {
        if (t < 15) stage(t + 1, ksN, vtN);

#pragma unroll
        for (int c = 0; c < 4; ++c) {
            uint4 kf[4];
#pragma unroll
            for (int dh = 0; dh < 4; ++dh)
                kf[dh] = *(const uint4*)&ksC[(c * 32 + l31) * 64 +
                                             (((dh * 2 + h) ^ (l31 & 7)) * 8)];
            unsigned E0[4][2], E1[4][2];
#pragma unroll
            for (int u = 0; u < 2; ++u) {
                f32x16 s;
#pragma unroll
                for (int r = 0; r < 16; ++r) s[r] = 0.f;
                __builtin_amdgcn_s_setprio(1);
#pragma unroll
                for (int dh = 0; dh < 4; ++dh) s = mfma32(kf[dh], qf[u][dh], s);
                __builtin_amdgcn_s_setprio(0);
                float lsum = 0.f;
#pragma unroll
                for (int g = 0; g < 4; ++g) {
                    float e0 = EXP2F(s[4 * g + 0]);
                    float e1 = EXP2F(s[4 * g + 1]);
                    float e2 = EXP2F(s[4 * g + 2]);
                    float e3 = EXP2F(s[4 * g + 3]);
                    lsum += (e0 + e1) + (e2 + e3);
                    if (u == 0) { E0[g][0] = pk_bf16(e0, e1); E0[g][1] = pk_bf16(e2, e3); }
                    else        { E1[g][0] = pk_bf16(e0, e1); E1[g][1] = pk_bf16(e2, e3); }
                }
                if (u == 0) l_acc0 += lsum; else l_acc1 += lsum;
            }
#pragma unroll
            for (int tau = 0; tau < 2; ++tau) {
                const int pos = ((c * 4 + tau * 2 + h) ^ (l31 & 15)) * 8;
                uint4 vf0 = *(const uint4*)&vtC[(size_t)l31 * 128 + pos];
                uint4 vf1 = *(const uint4*)&vtC[(size_t)(32 + l31) * 128 + pos];
                {
                    unsigned x0 = E0[2 * tau][0], z0 = E0[2 * tau + 1][0];
                    unsigned x1 = E0[2 * tau][1], z1 = E0[2 * tau + 1][1];
                    permswap32(x0, z0);
                    permswap32(x1, z1);
                    uint4 pf; pf.x = x0; pf.y = x1; pf.z = z0; pf.w = z1;
                    __builtin_amdgcn_s_setprio(1);
                    o00 = mfma32(vf0, pf, o00);
                    o01 = mfma32(vf1, pf, o01);
                    __builtin_amdgcn_s_setprio(0);
                }
                {
                    unsigned x0 = E1[2 * tau][0], z0 = E1[2 * tau + 1][0];
                    unsigned x1 = E1[2 * tau][1], z1 = E1[2 * tau + 1][1];
                    permswap32(x0, z0);
                    permswap32(x1, z1);
                    uint4 pf; pf.x = x0; pf.y = x1; pf.z = z0; pf.w = z1;
                    __builtin_amdgcn_s_setprio(1);
                    o10 = mfma32(vf0, pf, o10);
                    o11 = mfma32(vf1, pf, o11);
                    __builtin_amdgcn_s_setprio(0);
                }
            }
        }

        __syncthreads();
        unsigned short* tk = ksC; ksC = ksN; ksN = tk;
        unsigned short* tv = vtC; vtC = vtN; vtN = tv;
    }

    unsigned* ep = (unsigned*)smem + w * 1088;
#pragma unroll
    for (int u = 0; u < 2; ++u) {
        const float la = u ? l_acc1 : l_acc0;
        const float l_tot = la + __shfl_xor(la, 32, 64);
        const float rl = 1.f / l_tot;
#pragma unroll
        for (int dt = 0; dt < 2; ++dt) {
            const f32x16& o = u ? (dt ? o11 : o10) : (dt ? o01 : o00);
#pragma unroll
            for (int g = 0; g < 4; ++g)
#pragma unroll
                for (int p = 0; p < 2; ++p) {
                    const int dv = dt * 16 + 4 * g + 2 * h + p;
                    ep[l31 * 34 + dv] =
                        pk_bf16(o[4 * g + 2 * p] * rl, o[4 * g + 2 * p + 1] * rl);
                }
        }
        __builtin_amdgcn_s_waitcnt(0);
#pragma unroll
        for (int p = 0; p < 4; ++p) {
            const int qr = (lane >> 3) + p * 8;
            const int cch = lane & 7;
            uint4 vv = *(const uint4*)((const unsigned short*)ep + qr * 68 + cch * 8);
            *(uint4*)(ctx + (size_t)(b * L_SEQ + qbase + u * 32 + qr) * 2048 +
                      hq * 64 + cch * 8) = vv;
        }
        __builtin_amdgcn_s_waitcnt(0);
    }
}

// ---------------------------------------------------------------------------

extern "C" void kernel_launch(void* const* d_in, const int* in_sizes, int n_in,
                              void* d_out, int out_size, void* d_ws, size_t ws_size,
                              hipStream_t stream) {
    const float* x  = (const float*)d_in[0];
    const float* Wq = (const float*)d_in[1];
    const float* bq = (const float*)d_in[2];
    const float* Wk = (const float*)d_in[3];
    const float* bk = (const float*)d_in[4];
    const float* Wv = (const float*)d_in[5];
    const float* bv = (const float*)d_in[6];
    const float* Wo = (const float*)d_in[7];
    const float* bo = (const float*)d_in[8];
    float* out = (float*)d_out;

    char* ws = (char*)d_ws;
    size_t off = 0;
    auto alloc = [&](size_t bytes) {
        char* p = ws + off;
        off += (bytes + 255) & ~(size_t)255;
        return p;
    };
    unsigned short* Wqkvt = (unsigned short*)alloc((size_t)3072 * 2048 * 2);
    unsigned short* Wot   = (unsigned short*)alloc((size_t)2048 * 2048 * 2);
    unsigned short* Xb    = (unsigned short*)alloc((size_t)M_ROWS * 2048 * 2);
    unsigned short* Qb    = (unsigned short*)alloc((size_t)M_ROWS * 2048 * 2);
    unsigned short* Kb    = (unsigned short*)alloc((size_t)M_ROWS * KV_COLS * 2);
    unsigned short* Vb    = (unsigned short*)alloc((size_t)M_ROWS * KV_COLS * 2);
    unsigned short* Vt    = (unsigned short*)alloc((size_t)M_ROWS * KV_COLS * 2);
    unsigned short* Cb    = Xb;   // Xb dead after GEMM1; attn writes ctx here

    cast_x_kernel<<<(M_ROWS * 2048 / 4 + 255) / 256, 256, 0, stream>>>(x, Xb,
                                                                       M_ROWS * 2048 / 4);
    transpose_cast_kernel<<<dim3(64, 64), 256, 0, stream>>>(Wq, Wqkvt, 2048, 0);
    transpose_cast_kernel<<<dim3(16, 64), 256, 0, stream>>>(Wk, Wqkvt, 512, 2048);
    transpose_cast_kernel<<<dim3(16, 64), 256, 0, stream>>>(Wv, Wqkvt, 512, 2560);
    transpose_cast_kernel<<<dim3(64, 64), 256, 0, stream>>>(Wo, Wot, 2048, 0);
    gemm_qkv_kernel<<<dim3(16, 12), 512, 0, stream>>>(Xb, Wqkvt, bq, bk, bv, Qb, Kb, Vb);
    transpose_v_kernel<<<dim3(16, 64, 2), 256, 0, stream>>>(Vb, Vt);
    attn_kernel<<<dim3(4, 32, 2), 512, 0, stream>>>(Qb, Kb, Vt, Cb);
    gemm_out_kernel<<<dim3(32, 8), 512, 0, stream>>>(Cb, Wot, bo, out);
}

// Round 8
// 310.489 us; speedup vs baseline: 1.0484x; 1.0484x over previous
//
#include <hip/hip_runtime.h>
#include <cstdint>
#include <cstring>

// ---------------------------------------------------------------------------
// GQA forward, all-bf16 MFMA pipeline.  B=2, L=2048, D=2048, HQ=32, HKV=8, HD=64.
// Round 12: GEMMs rebuilt as counted-vmcnt 3-ring pipelines (T3+T4 mechanism).
//   - Both GEMMs: 128x128 tile, BK=64, 512 thr (8 waves, 2m x 4n), 3-slot LDS
//     ring (96 KB).  Per K-tile: s_waitcnt vmcnt(4) [own tile-t loads done,
//     tile-t+1's 4 loads STAY IN FLIGHT] -> raw s_barrier -> issue tile t+2
//     -> 12 ds_read_b128 + 16 MFMA (setprio).  Drain to 0 only at t=31.
//     No __syncthreads vmcnt(0) drain anywhere in the main loop.
//   - Grids 32x24=768 (3 clean rounds of 256 CUs) and 32x16=512 (2 rounds);
//     R11's 192-block gemm_qkv left 25% of the chip idle.
//   - Race audit: stage(t+2) targets slot (t-1)%3, whose readers (iter t-1
//     compute) all passed the iter-t barrier; RAW certified per-wave by the
//     pre-barrier vmcnt, block-visible after the barrier.
//   - attn + prep kernels: exactly the verified Round-7/11 code (~108 us attn).
// ---------------------------------------------------------------------------

#define L_SEQ 2048
#define D_MODEL 2048
#define M_ROWS 4096              // B*L
#define KV_COLS 512              // HKV*HD
#define ATTN_SCALE 0.18033688011112042f   // log2(e)/sqrt(64), folded into K

typedef __bf16 bf16x8 __attribute__((ext_vector_type(8)));
typedef float f32x4 __attribute__((ext_vector_type(4)));
typedef float f32x16 __attribute__((ext_vector_type(16)));

__device__ __forceinline__ f32x4 zero4() {
    f32x4 v; v[0] = 0.f; v[1] = 0.f; v[2] = 0.f; v[3] = 0.f; return v;
}

__device__ __forceinline__ unsigned short f2bf(float x) {
    unsigned u = __builtin_bit_cast(unsigned, x);
    u = (u + 0x7FFFu + ((u >> 16) & 1u)) >> 16;   // RNE
    return (unsigned short)u;
}

__device__ __forceinline__ unsigned pk_bf16(float a, float b) {
#if __has_builtin(__builtin_amdgcn_cvt_pk_bf16_f32)
    typedef __bf16 bf16x2 __attribute__((ext_vector_type(2)));
    bf16x2 r = __builtin_amdgcn_cvt_pk_bf16_f32(a, b);
    return __builtin_bit_cast(unsigned, r);
#else
    return (unsigned)f2bf(a) | ((unsigned)f2bf(b) << 16);
#endif
}

__device__ __forceinline__ f32x4 mfma16(uint4 a, uint4 b, f32x4 c) {
    return __builtin_amdgcn_mfma_f32_16x16x32_bf16(
        __builtin_bit_cast(bf16x8, a), __builtin_bit_cast(bf16x8, b), c, 0, 0, 0);
}
__device__ __forceinline__ f32x16 mfma32(uint4 a, uint4 b, f32x16 c) {
    return __builtin_amdgcn_mfma_f32_32x32x16_bf16(
        __builtin_bit_cast(bf16x8, a), __builtin_bit_cast(bf16x8, b), c, 0, 0, 0);
}

__device__ __forceinline__ void gl_lds16(const unsigned short* g, unsigned short* l) {
    __builtin_amdgcn_global_load_lds(
        (const __attribute__((address_space(1))) unsigned int*)g,
        (__attribute__((address_space(3))) unsigned int*)l, 16, 0, 0);
}

#if __has_builtin(__builtin_amdgcn_exp2f)
#define EXP2F(x) __builtin_amdgcn_exp2f(x)
#else
#define EXP2F(x) exp2f(x)
#endif

// a.hi <-> b.lo lane exchange
__device__ __forceinline__ void permswap32(unsigned& a, unsigned& b) {
    asm("v_permlane32_swap_b32 %0, %1" : "+v"(a), "+v"(b));
}

// ---------------------------------------------------------------------------
// prep kernels
// ---------------------------------------------------------------------------

__global__ __launch_bounds__(256) void cast_x_kernel(const float* __restrict__ in,
                                                     unsigned short* __restrict__ out,
                                                     int n4) {
    int i = blockIdx.x * 256 + threadIdx.x;
    if (i >= n4) return;
    float4 v = ((const float4*)in)[i];
    uint2 o;
    o.x = pk_bf16(v.x, v.y);
    o.y = pk_bf16(v.z, v.w);
    ((uint2*)out)[i] = o;
}

__global__ __launch_bounds__(256) void transpose_cast_kernel(const float* __restrict__ in,
                                                             unsigned short* __restrict__ out,
                                                             int N, int row_off) {
    __shared__ float tile[32][33];
    const int n0 = blockIdx.x * 32, k0 = blockIdx.y * 32;
    const int tc = threadIdx.x & 31, tr = threadIdx.x >> 5;
#pragma unroll
    for (int i = 0; i < 4; ++i)
        tile[tr + i * 8][tc] = in[(size_t)(k0 + tr + i * 8) * N + n0 + tc];
    __syncthreads();
#pragma unroll
    for (int i = 0; i < 4; ++i)
        out[(size_t)(row_off + n0 + tr + i * 8) * 2048 + k0 + tc] = f2bf(tile[tc][tr + i * 8]);
}

// Vb [B*L, 512] bf16  ->  Vt [(b*8+kvh)*64+d, 2048] bf16  (per-b transpose)
__global__ __launch_bounds__(256) void transpose_v_kernel(const unsigned short* __restrict__ Vb,
                                                          unsigned short* __restrict__ Vt) {
    __shared__ unsigned short tile[32][33];
    const int c0 = blockIdx.x * 32, l0 = blockIdx.y * 32, b = blockIdx.z;
    const int tc = threadIdx.x & 31, tr = threadIdx.x >> 5;
#pragma unroll
    for (int i = 0; i < 4; ++i)
        tile[tr + i * 8][tc] = Vb[(size_t)(b * 2048 + l0 + tr + i * 8) * KV_COLS + c0 + tc];
    __syncthreads();
#pragma unroll
    for (int i = 0; i < 4; ++i)
        Vt[(size_t)(b * 512 + c0 + tr + i * 8) * 2048 + l0 + tc] = tile[tc][tr + i * 8];
}

// ---------------------------------------------------------------------------
// Counted-vmcnt ring GEMM core: C[128x128] = A[*,2048] * Bt[*,2048]^T
// 512 thr, 8 waves (2m x 4n, per-wave 64x32 = acc[4][2]).
// 3-slot ring (3 x 32 KB); slot = A[128][64] (16 KB) + B[128][64] (16 KB).
// Per K-tile: vmcnt(4) -> s_barrier -> stage(t+2) -> 12 ds_read + 16 mfma.
// ---------------------------------------------------------------------------

__device__ __forceinline__ void gemm_ring_core(const unsigned short* __restrict__ A,
                                               const unsigned short* __restrict__ Bt,
                                               int arow0, int brow0,
                                               char* smem, f32x4 acc[4][2]) {
    const int tid = threadIdx.x;
    const int w = tid >> 6, lane = tid & 63;
    const int wm = w >> 2, wn = w & 3;
    const int lr = lane & 15, lg = lane >> 4;
    const int rr = lane >> 3, cp = lane & 7;

#pragma unroll
    for (int i = 0; i < 4; ++i)
#pragma unroll
        for (int j = 0; j < 2; ++j) acc[i][j] = zero4();

    // stage K-tile kt into ring slot: A 16 chunk-blocks (8 rows x 128B) + B 16
    auto stage = [&](int kt, int slot) {
        char* base = smem + slot * 32768;
        const int k8 = kt * 64 + ((cp ^ rr) * 8);
#pragma unroll
        for (int s = 0; s < 2; ++s) {
            const int c = w * 2 + s;
            gl_lds16(A + (size_t)(arow0 + c * 8 + rr) * 2048 + k8,
                     (unsigned short*)(base + c * 1024));
            gl_lds16(Bt + (size_t)(brow0 + c * 8 + rr) * 2048 + k8,
                     (unsigned short*)(base + 16384 + c * 1024));
        }
    };

    stage(0, 0);
    stage(1, 1);

    for (int t = 0; t < 32; ++t) {
        // certify own tile-t loads (4 oldest); tile-t+1's 4 stay in flight
        if (t < 31) asm volatile("s_waitcnt vmcnt(4)" ::: "memory");
        else        asm volatile("s_waitcnt vmcnt(0)" ::: "memory");
        __builtin_amdgcn_s_barrier();   // all waves certified -> tile t visible
        asm volatile("" ::: "memory");

        if (t <= 29) stage(t + 2, (t + 2) % 3);   // slot (t-1)%3: readers done

        const char* Ab = smem + (t % 3) * 32768;
        const char* Bb = Ab + 16384;

        uint4 fa[4][2], fb[2][2];
#pragma unroll
        for (int mi = 0; mi < 4; ++mi) {
            const int row = wm * 64 + mi * 16 + lr;
#pragma unroll
            for (int ks = 0; ks < 2; ++ks)
                fa[mi][ks] = *(const uint4*)(Ab + row * 128 +
                                             (((ks * 4 + lg) ^ (lr & 7)) * 16));
        }
#pragma unroll
        for (int nj = 0; nj < 2; ++nj) {
            const int row = wn * 32 + nj * 16 + lr;
#pragma unroll
            for (int ks = 0; ks < 2; ++ks)
                fb[nj][ks] = *(const uint4*)(Bb + row * 128 +
                                             (((ks * 4 + lg) ^ (lr & 7)) * 16));
        }
        __builtin_amdgcn_s_setprio(1);
#pragma unroll
        for (int mi = 0; mi < 4; ++mi)
#pragma unroll
            for (int nj = 0; nj < 2; ++nj) {
                acc[mi][nj] = mfma16(fa[mi][0], fb[nj][0], acc[mi][nj]);
                acc[mi][nj] = mfma16(fa[mi][1], fb[nj][1], acc[mi][nj]);
            }
        __builtin_amdgcn_s_setprio(0);
    }
}

// GEMM1: X*[Wq|Wk|Wv] + bias -> Q [4096,2048], K [4096,512] (pre-scaled),
// V [4096,512].  Grid 32 x 24 = 768 blocks (3 clean rounds of 256 CUs).
__global__ __launch_bounds__(512, 1) void gemm_qkv_kernel(
    const unsigned short* __restrict__ Xb, const unsigned short* __restrict__ Wt,
    const float* __restrict__ bq, const float* __restrict__ bk, const float* __restrict__ bv,
    unsigned short* __restrict__ Qb, unsigned short* __restrict__ Kb,
    unsigned short* __restrict__ Vb) {
    __shared__ __align__(16) char smem[98304];   // 3 x 32 KB ring

    const int mb = blockIdx.x, nb = blockIdx.y;
    f32x4 acc[4][2];
    gemm_ring_core(Xb, Wt, mb * 128, nb * 128, smem, acc);

    const int tid = threadIdx.x;
    const int w = tid >> 6, lane = tid & 63;
    const int wm = w >> 2, wn = w & 3;
    const int lr = lane & 15, lg = lane >> 4;

    const int nbase = nb * 128;
    unsigned short* outp; int ldo, noff; const float* bias; float scale;
    if (nbase < 2048)      { outp = Qb; ldo = 2048; noff = 0;    bias = bq; scale = 1.f; }
    else if (nbase < 2560) { outp = Kb; ldo = 512;  noff = 2048; bias = bk; scale = ATTN_SCALE; }
    else                   { outp = Vb; ldo = 512;  noff = 2560; bias = bv; scale = 1.f; }

    __syncthreads();   // all waves done reading ring; safe to repurpose LDS
    float* ep = (float*)(smem + (size_t)w * 8192);   // [64 rows][32 cols] f32
#pragma unroll
    for (int mi = 0; mi < 4; ++mi)
#pragma unroll
        for (int nj = 0; nj < 2; ++nj)
#pragma unroll
            for (int r = 0; r < 4; ++r)
                ep[(mi * 16 + lg * 4 + r) * 32 + nj * 16 + lr] = acc[mi][nj][r];
    __builtin_amdgcn_s_waitcnt(0);   // wave-local LDS write->read ordering
#pragma unroll
    for (int p = 0; p < 4; ++p) {
        const int row = p * 16 + (lane >> 2);
        const int cc = lane & 3;
        const float* v = ep + row * 32 + cc * 8;
        const float4 va = *(const float4*)v;
        const float4 vb2 = *(const float4*)(v + 4);
        const int nloc = nbase + wn * 32 + cc * 8 - noff;
        const float4 b0 = *(const float4*)(bias + nloc);
        const float4 b1 = *(const float4*)(bias + nloc + 4);
        uint4 o;
        o.x = pk_bf16((va.x + b0.x) * scale, (va.y + b0.y) * scale);
        o.y = pk_bf16((va.z + b0.z) * scale, (va.w + b0.w) * scale);
        o.z = pk_bf16((vb2.x + b1.x) * scale, (vb2.y + b1.y) * scale);
        o.w = pk_bf16((vb2.z + b1.z) * scale, (vb2.w + b1.w) * scale);
        *(uint4*)(outp + (size_t)(mb * 128 + wm * 64 + row) * ldo + nloc) = o;
    }
}

// GEMM2: ctx * Wo^T + bo -> fp32 out [4096,2048].
// Grid 32 x 16 = 512 blocks (2 clean rounds of 256 CUs).
__global__ __launch_bounds__(512, 1) void gemm_out_kernel(
    const unsigned short* __restrict__ Cb, const unsigned short* __restrict__ Wot,
    const float* __restrict__ bo, float* __restrict__ out) {
    __shared__ __align__(16) char smem[98304];   // 3 x 32 KB ring

    const int mb = blockIdx.x, nb = blockIdx.y;
    f32x4 acc[4][2];
    gemm_ring_core(Cb, Wot, mb * 128, nb * 128, smem, acc);

    const int tid = threadIdx.x;
    const int w = tid >> 6, lane = tid & 63;
    const int wm = w >> 2, wn = w & 3;
    const int lr = lane & 15, lg = lane >> 4;

#pragma unroll
    for (int mi = 0; mi < 4; ++mi) {
        const int mrow = mb * 128 + wm * 64 + mi * 16 + lg * 4;
#pragma unroll
        for (int nj = 0; nj < 2; ++nj) {
            const int ncol = nb * 128 + wn * 32 + nj * 16 + lr;
            const float bb = bo[ncol];
#pragma unroll
            for (int r = 0; r < 4; ++r)
                out[(size_t)(mrow + r) * 2048 + ncol] = acc[mi][nj][r] + bb;
        }
    }
}

// ---------------------------------------------------------------------------
// Attention (Round-7 verified): block = 512 thr = 8 waves; each wave owns
// 64 q (2 q-frags, u=0/1) of one q-head; block covers 512 q.  Grid
// 4 x 32 x 2 = 256 blocks.  K tile [128 k][64 d] and V^T tile [64 d][128 k]
// double-buffered (64 KB LDS); next tile staged before compute; one
// __syncthreads per iter.  permswap P assembly; setprio around MFMA.
// ---------------------------------------------------------------------------

__global__ __launch_bounds__(512, 2) void attn_kernel(const unsigned short* __restrict__ Qb,
                                                      const unsigned short* __restrict__ Kb,
                                                      const unsigned short* __restrict__ Vtg,
                                                      unsigned short* __restrict__ ctx) {
    __shared__ __align__(16) unsigned short smem[32768];   // 64 KB

    const int qt = blockIdx.x, hq = blockIdx.y, b = blockIdx.z;
    const int kvh = hq >> 2;
    const int tid = threadIdx.x;
    const int w = tid >> 6, lane = tid & 63;
    const int l31 = lane & 31, h = lane >> 5;

    const int qbase = qt * 512 + w * 64;
    uint4 qf[2][4];
#pragma unroll
    for (int u = 0; u < 2; ++u) {
        const unsigned short* qp =
            Qb + (size_t)(b * L_SEQ + qbase + u * 32 + l31) * 2048 + hq * 64;
#pragma unroll
        for (int dh = 0; dh < 4; ++dh)
            qf[u][dh] = *(const uint4*)(qp + dh * 16 + h * 8);
    }

    f32x16 o00, o01, o10, o11;
#pragma unroll
    for (int r = 0; r < 16; ++r) { o00[r] = 0.f; o01[r] = 0.f; o10[r] = 0.f; o11[r] = 0.f; }
    float l_acc0 = 0.f, l_acc1 = 0.f;

    const size_t kbase = (size_t)(b * L_SEQ) * KV_COLS + kvh * 64;
    const size_t vbase = (size_t)((b * 8 + kvh) * 64) * 2048;

    const int rrk = lane >> 3, cpk = lane & 7;
    const int drv = lane >> 4, cpv = lane & 15;

    unsigned short* ksC = smem;
    unsigned short* vtC = smem + 8192;
    unsigned short* ksN = smem + 16384;
    unsigned short* vtN = smem + 24576;

    auto stage = [&](int T, unsigned short* KS, unsigned short* VT) {
        const int k0s = T * 128;
#pragma unroll
        for (int s = 0; s < 2; ++s) {
            const int blk = w * 2 + s;
            gl_lds16(Kb + kbase + (size_t)(k0s + blk * 8 + rrk) * KV_COLS + ((cpk ^ rrk) * 8),
                     KS + blk * 512);
            const int d = blk * 4 + drv;
            gl_lds16(Vtg + vbase + (size_t)d * 2048 + k0s + ((cpv ^ (d & 15)) * 8),
                     VT + blk * 512);
        }
    };

    stage(0, ksC, vtC);
    __syncthreads();

    for (int t = 0; t < 16; ++t) {
        if (t < 15) stage(t + 1, ksN, vtN);

#pragma unroll
        for (int c = 0; c < 4; ++c) {
            uint4 kf[4];
#pragma unroll
            for (int dh = 0; dh < 4; ++dh)
                kf[dh] = *(const uint4*)&ksC[(c * 32 + l31) * 64 +
                                             (((dh * 2 + h) ^ (l31 & 7)) * 8)];
            unsigned E0[4][2], E1[4][2];
#pragma unroll
            for (int u = 0; u < 2; ++u) {
                f32x16 s;
#pragma unroll
                for (int r = 0; r < 16; ++r) s[r] = 0.f;
                __builtin_amdgcn_s_setprio(1);
#pragma unroll
                for (int dh = 0; dh < 4; ++dh) s = mfma32(kf[dh], qf[u][dh], s);
                __builtin_amdgcn_s_setprio(0);
                float lsum = 0.f;
#pragma unroll
                for (int g = 0; g < 4; ++g) {
                    float e0 = EXP2F(s[4 * g + 0]);
                    float e1 = EXP2F(s[4 * g + 1]);
                    float e2 = EXP2F(s[4 * g + 2]);
                    float e3 = EXP2F(s[4 * g + 3]);
                    lsum += (e0 + e1) + (e2 + e3);
                    if (u == 0) { E0[g][0] = pk_bf16(e0, e1); E0[g][1] = pk_bf16(e2, e3); }
                    else        { E1[g][0] = pk_bf16(e0, e1); E1[g][1] = pk_bf16(e2, e3); }
                }
                if (u == 0) l_acc0 += lsum; else l_acc1 += lsum;
            }
#pragma unroll
            for (int tau = 0; tau < 2; ++tau) {
                const int pos = ((c * 4 + tau * 2 + h) ^ (l31 & 15)) * 8;
                uint4 vf0 = *(const uint4*)&vtC[(size_t)l31 * 128 + pos];
                uint4 vf1 = *(const uint4*)&vtC[(size_t)(32 + l31) * 128 + pos];
                {
                    unsigned x0 = E0[2 * tau][0], z0 = E0[2 * tau + 1][0];
                    unsigned x1 = E0[2 * tau][1], z1 = E0[2 * tau + 1][1];
                    permswap32(x0, z0);
                    permswap32(x1, z1);
                    uint4 pf; pf.x = x0; pf.y = x1; pf.z = z0; pf.w = z1;
                    __builtin_amdgcn_s_setprio(1);
                    o00 = mfma32(vf0, pf, o00);
                    o01 = mfma32(vf1, pf, o01);
                    __builtin_amdgcn_s_setprio(0);
                }
                {
                    unsigned x0 = E1[2 * tau][0], z0 = E1[2 * tau + 1][0];
                    unsigned x1 = E1[2 * tau][1], z1 = E1[2 * tau + 1][1];
                    permswap32(x0, z0);
                    permswap32(x1, z1);
                    uint4 pf; pf.x = x0; pf.y = x1; pf.z = z0; pf.w = z1;
                    __builtin_amdgcn_s_setprio(1);
                    o10 = mfma32(vf0, pf, o10);
                    o11 = mfma32(vf1, pf, o11);
                    __builtin_amdgcn_s_setprio(0);
                }
            }
        }

        __syncthreads();
        unsigned short* tk = ksC; ksC = ksN; ksN = tk;
        unsigned short* tv = vtC; vtC = vtN; vtN = tv;
    }

    unsigned* ep = (unsigned*)smem + w * 1088;
#pragma unroll
    for (int u = 0; u < 2; ++u) {
        const float la = u ? l_acc1 : l_acc0;
        const float l_tot = la + __shfl_xor(la, 32, 64);
        const float rl = 1.f / l_tot;
#pragma unroll
        for (int dt = 0; dt < 2; ++dt) {
            const f32x16& o = u ? (dt ? o11 : o10) : (dt ? o01 : o00);
#pragma unroll
            for (int g = 0; g < 4; ++g)
#pragma unroll
                for (int p = 0; p < 2; ++p) {
                    const int dv = dt * 16 + 4 * g + 2 * h + p;
                    ep[l31 * 34 + dv] =
                        pk_bf16(o[4 * g + 2 * p] * rl, o[4 * g + 2 * p + 1] * rl);
                }
        }
        __builtin_amdgcn_s_waitcnt(0);
#pragma unroll
        for (int p = 0; p < 4; ++p) {
            const int qr = (lane >> 3) + p * 8;
            const int cch = lane & 7;
            uint4 vv = *(const uint4*)((const unsigned short*)ep + qr * 68 + cch * 8);
            *(uint4*)(ctx + (size_t)(b * L_SEQ + qbase + u * 32 + qr) * 2048 +
                      hq * 64 + cch * 8) = vv;
        }
        __builtin_amdgcn_s_waitcnt(0);
    }
}

// ---------------------------------------------------------------------------

extern "C" void kernel_launch(void* const* d_in, const int* in_sizes, int n_in,
                              void* d_out, int out_size, void* d_ws, size_t ws_size,
                              hipStream_t stream) {
    const float* x  = (const float*)d_in[0];
    const float* Wq = (const float*)d_in[1];
    const float* bq = (const float*)d_in[2];
    const float* Wk = (const float*)d_in[3];
    const float* bk = (const float*)d_in[4];
    const float* Wv = (const float*)d_in[5];
    const float* bv = (const float*)d_in[6];
    const float* Wo = (const float*)d_in[7];
    const float* bo = (const float*)d_in[8];
    float* out = (float*)d_out;

    char* ws = (char*)d_ws;
    size_t off = 0;
    auto alloc = [&](size_t bytes) {
        char* p = ws + off;
        off += (bytes + 255) & ~(size_t)255;
        return p;
    };
    unsigned short* Wqkvt = (unsigned short*)alloc((size_t)3072 * 2048 * 2);
    unsigned short* Wot   = (unsigned short*)alloc((size_t)2048 * 2048 * 2);
    unsigned short* Xb    = (unsigned short*)alloc((size_t)M_ROWS * 2048 * 2);
    unsigned short* Qb    = (unsigned short*)alloc((size_t)M_ROWS * 2048 * 2);
    unsigned short* Kb    = (unsigned short*)alloc((size_t)M_ROWS * KV_COLS * 2);
    unsigned short* Vb    = (unsigned short*)alloc((size_t)M_ROWS * KV_COLS * 2);
    unsigned short* Vt    = (unsigned short*)alloc((size_t)M_ROWS * KV_COLS * 2);
    unsigned short* Cb    = Xb;   // Xb dead after GEMM1; attn writes ctx here

    cast_x_kernel<<<(M_ROWS * 2048 / 4 + 255) / 256, 256, 0, stream>>>(x, Xb,
                                                                       M_ROWS * 2048 / 4);
    transpose_cast_kernel<<<dim3(64, 64), 256, 0, stream>>>(Wq, Wqkvt, 2048, 0);
    transpose_cast_kernel<<<dim3(16, 64), 256, 0, stream>>>(Wk, Wqkvt, 512, 2048);
    transpose_cast_kernel<<<dim3(16, 64), 256, 0, stream>>>(Wv, Wqkvt, 512, 2560);
    transpose_cast_kernel<<<dim3(64, 64), 256, 0, stream>>>(Wo, Wot, 2048, 0);
    gemm_qkv_kernel<<<dim3(32, 24), 512, 0, stream>>>(Xb, Wqkvt, bq, bk, bv, Qb, Kb, Vb);
    transpose_v_kernel<<<dim3(16, 64, 2), 256, 0, stream>>>(Vb, Vt);
    attn_kernel<<<dim3(4, 32, 2), 512, 0, stream>>>(Qb, Kb, Vt, Cb);
    gemm_out_kernel<<<dim3(32, 16), 512, 0, stream>>>(Cb, Wot, bo, out);
}